// Round 1
// 191.326 us; speedup vs baseline: 1.0069x; 1.0069x over previous
//
#include <hip/hip_runtime.h>

// Problem constants (reference: B=32 graphs, n=128 nodes/graph, D=64, E=65536)
constexpr int NPG    = 128;
constexpr int DIM    = 64;
constexpr int NNODE  = 32 * NPG;       // 4096
constexpr int TWO_D  = 2 * DIM;        // 128
constexpr int CAP    = 96;             // bucket capacity per row (Poisson(16) tail ~1e-18)
constexpr int WT_LD  = DIM + 1;        // 65: pad so staging writes + reads are bank-conflict-free

typedef float f32x4 __attribute__((ext_vector_type(4)));

// ---------------------------------------------------------------------------
// K1: u/v projection.  ub[i][d] = b[d] + sum_k x[i][k]*W[d][k]
//                      v [i][d] =        sum_k x[i][k]*W[d][k+64]
// Grid 1024 x 256: one wave per node, 4 nodes/block -> 4 blocks/CU (vs 1
// before), single barrier (vs 8). WT padded to ld=65: the staging write
// (lanes vary k at fixed d, stride 64*4B -> one bank) was ~23x serialized;
// with ld=65 both writes (k varies) and reads (d varies) hit distinct banks.
// Also zeroes the 4096 per-row edge counters (ws arrives poisoned 0xAA).
// ---------------------------------------------------------------------------
__global__ __launch_bounds__(256) void uv_kernel(const float* __restrict__ x,
                                                 const float* __restrict__ W,
                                                 const float* __restrict__ b,
                                                 float* __restrict__ ub,
                                                 float* __restrict__ v,
                                                 int* __restrict__ cnt) {
    if (blockIdx.x < 16) cnt[blockIdx.x * 256 + threadIdx.x] = 0;

    __shared__ float WT[TWO_D * WT_LD];   // WT[k*65 + d] = W[d*128 + k]  (33.3 KiB)
    __shared__ float xs[4][DIM];

    const int d     = threadIdx.x & 63;
    const int local = threadIdx.x >> 6;   // 0..3 (one wave per node)
    const int node  = blockIdx.x * 4 + local;

    // coalesced read of W, conflict-free LDS write ((65k+d)%32 == (k+d)%32)
    for (int idx = threadIdx.x; idx < DIM * TWO_D; idx += 256) {
        const int dd = idx >> 7;     // 0..63
        const int k  = idx & 127;    // 0..127
        WT[k * WT_LD + dd] = W[idx];
    }
    xs[local][d] = x[node * DIM + d];
    const float bb = b[d];
    __syncthreads();

    float su = 0.f, sv = 0.f;
#pragma unroll
    for (int k = 0; k < DIM; ++k) {
        const float xv = xs[local][k];               // wave-uniform addr: LDS broadcast
        su = fmaf(xv, WT[k * WT_LD + d], su);        // conflict-free (d varies)
        sv = fmaf(xv, WT[(k + DIM) * WT_LD + d], sv);
    }
    ub[node * DIM + d] = su + bb;
    v [node * DIM + d] = sv;
}

// ---------------------------------------------------------------------------
// K2: bucket edges by destination row i0.  entry = (e << 7) | lj.
// ---------------------------------------------------------------------------
__global__ __launch_bounds__(256) void bucket_kernel(const int* __restrict__ ei,
                                                     int* __restrict__ cnt,
                                                     unsigned* __restrict__ bucket,
                                                     int E) {
    const int e = blockIdx.x * 256 + threadIdx.x;
    if (e >= E) return;
    const int i0 = ei[e];
    const int lj = ei[E + e] & (NPG - 1);
    const int slot = atomicAdd(&cnt[i0], 1);
    if (slot < CAP) bucket[i0 * CAP + slot] = ((unsigned)e << 7) | (unsigned)lj;
}

// ---------------------------------------------------------------------------
// K3: fused fill + edge merge. One block per output row (g*128+i).
// Phase 1 (cheap, pre-barrier): zero 32 KiB LDS tile, scatter this row's ~16
// edges into it via ds_add_f32. Phase 2 (barrier-free stream): write
// out = u[row] + v[col] + tile, coalesced float4.
// cnt/ub loads hoisted above the zero-loop so their latency hides under it.
// ea loads and out stores are nontemporal: both are touch-once streams, so
// keep them out of L2/MALL and leave v/bucket/cnt resident.
// ---------------------------------------------------------------------------
__global__ __launch_bounds__(256) void fill_kernel(const float* __restrict__ ub,
                                                   const float* __restrict__ v,
                                                   const float* __restrict__ ea,
                                                   const int* __restrict__ cnt,
                                                   const unsigned* __restrict__ bucket,
                                                   float* __restrict__ out) {
    __shared__ float tile[NPG * DIM];   // 32 KiB: sparse edge contributions
    const int row = blockIdx.x;         // 0..4095
    const int g   = row >> 7;
    const int t   = threadIdx.x;

    int n = cnt[row];                                                    // issue early
    const f32x4 u4 = ((const f32x4*)(ub + (size_t)row * DIM))[t & 15];   // issue early

    f32x4* tile4 = (f32x4*)tile;
    const f32x4 z = {0.f, 0.f, 0.f, 0.f};
#pragma unroll
    for (int it = 0; it < 8; ++it) tile4[it * 256 + t] = z;

    if (n > CAP) n = CAP;
    __syncthreads();

    // 16 edges in flight: threads (t>>4) pick the edge, (t&15) the float4 lane
    for (int base = 0; base < n; base += 16) {
        const int k = base + (t >> 4);
        if (k < n) {
            const unsigned p = bucket[row * CAP + k];
            const int lj = (int)(p & 127u);
            const int e  = (int)(p >> 7);
            const int c  = t & 15;
            const f32x4 a =
                __builtin_nontemporal_load(((const f32x4*)ea) + (size_t)e * 16 + c);
            float* dst = &tile[lj * DIM + c * 4];
            atomicAdd(dst + 0, a.x);    // ds_add_f32; dup (i0,lj) pairs exist
            atomicAdd(dst + 1, a.y);
            atomicAdd(dst + 2, a.z);
            atomicAdd(dst + 3, a.w);
        }
    }
    __syncthreads();

    const f32x4* __restrict__ vv = (const f32x4*)(v + (size_t)g * NPG * DIM);
    f32x4* __restrict__ ov       = (f32x4*)(out + (size_t)row * NPG * DIM);
#pragma unroll
    for (int it = 0; it < 8; ++it) {
        const int q = it * 256 + t;     // 2048 float4s = 8192 floats
        const f32x4 r = vv[q] + u4 + tile4[q];
        __builtin_nontemporal_store(r, &ov[q]);
    }
}

extern "C" void kernel_launch(void* const* d_in, const int* in_sizes, int n_in,
                              void* d_out, int out_size, void* d_ws, size_t ws_size,
                              hipStream_t stream) {
    const float* x  = (const float*)d_in[0];   // [4096, 64]
    const int*   ei = (const int*)  d_in[1];   // [2, E]
    const float* ea = (const float*)d_in[2];   // [E, 64]
    // d_in[3] = batch, d_in[4] = token_index — implied by dense layout
    const float* W  = (const float*)d_in[5];   // [64, 128]
    const float* b  = (const float*)d_in[6];   // [64]
    float* out = (float*)d_out;                // [32,128,128,64]

    float*    ub     = (float*)d_ws;                    // [4096,64]
    float*    v      = ub + NNODE * DIM;                // [4096,64]
    int*      cnt    = (int*)(v + NNODE * DIM);         // [4096]
    unsigned* bucket = (unsigned*)(cnt + NNODE);        // [4096,96]

    const int E = in_sizes[1] / 2;

    uv_kernel<<<1024, 256, 0, stream>>>(x, W, b, ub, v, cnt);
    bucket_kernel<<<(E + 255) / 256, 256, 0, stream>>>(ei, cnt, bucket, E);
    fill_kernel<<<NNODE, 256, 0, stream>>>(ub, v, ea, cnt, bucket, out);
}